// Round 1
// baseline (519.108 us; speedup 1.0000x reference)
//
#include <hip/hip_runtime.h>
#include <hip/hip_bf16.h>
#include <stdint.h>

// Problem constants (from reference)
#define B_   16
#define C_   512
#define T_   2048
#define O_   512

// Tiling
#define BM   64     // O tile
#define BNO  64     // T output tile
#define BNE  80     // T ext tile (halo 8 each side; taps need +-4)
#define BK   32     // K (channel) chunk == one MFMA K step
#define WSTRIDE 40  // LDS row stride in halves (32 + 8 pad -> bank-floor b128 reads)
#define QSTRIDE 84  // epilogue f32 row stride (80 + 4 pad -> 2-way free)

typedef _Float16 half4_t __attribute__((ext_vector_type(4)));
typedef _Float16 half8_t __attribute__((ext_vector_type(8)));
typedef float    f32x4   __attribute__((ext_vector_type(4)));

// ---------------- Kernel 1: split W into f16 hi/lo planes in workspace ----------------
// whi/wlo layout: [3][O_][C_] halves (matrix m: 0=q,1=k,2=v)
__global__ __launch_bounds__(256) void pack_w_kernel(
    const float* __restrict__ wq, const float* __restrict__ wk,
    const float* __restrict__ wv, _Float16* __restrict__ whi,
    _Float16* __restrict__ wlo) {
  int gid = blockIdx.x * 256 + threadIdx.x;   // 0..196607 (x4 elems = 3*512*512)
  int idx = gid * 4;
  int m   = idx >> 18;                        // / 262144
  int rem = idx & 262143;
  const float* src = (m == 0) ? wq : (m == 1) ? wk : wv;
  float4 xv = *reinterpret_cast<const float4*>(src + rem);
  float xs[4] = {xv.x, xv.y, xv.z, xv.w};
  half4_t h, l;
#pragma unroll
  for (int e = 0; e < 4; ++e) {
    _Float16 hi = (_Float16)xs[e];
    _Float16 lo = (_Float16)(xs[e] - (float)hi);
    h[e] = hi;
    l[e] = lo;
  }
  *reinterpret_cast<half4_t*>(whi + (size_t)m * 262144 + rem) = h;
  *reinterpret_cast<half4_t*>(wlo + (size_t)m * 262144 + rem) = l;
}

// ---------------- Kernel 2: fused QKV GEMM (f16 split MFMA) + 3-tap softmax ----------------
// grid: (O_/BM=8, T_/BNO=32, B_=16), block 256 (4 waves, wave w owns M-subtile w)
__global__ __launch_bounds__(256, 2) void fused_kernel(
    const float* __restrict__ x, const _Float16* __restrict__ whiG,
    const _Float16* __restrict__ wloG, float* __restrict__ out) {
  // staging: Whi/Wlo [3*64][WSTRIDE], Xhi/Xlo [80][WSTRIDE]  (43.5 KB)
  // epilogue: QKV [3*64][QSTRIDE] f32                        (64512 B) -- unioned
  __shared__ __align__(16) char smem[64512];
  _Float16* Whi = (_Float16*)smem;        // 3*64*40 = 7680 halves
  _Float16* Wlo = Whi + 7680;
  _Float16* Xhi = Wlo + 7680;             // 80*40 = 3200 halves
  _Float16* Xlo = Xhi + 3200;
  float* QKV = (float*)smem;              // 3*64*84 f32

  const int tid   = threadIdx.x;
  const int ob    = blockIdx.x;           // O tile (innermost -> 8 consecutive blocks share X tile in L2)
  const int tb    = blockIdx.y;           // T tile
  const int b     = blockIdx.z;
  const int obase = ob * BM;
  const int tbase = tb * BNO - 8;         // global t of ext column 0 (may be <0)
  const float* xb = x + (size_t)b * C_ * T_;

  const int lane = tid & 63;
  const int w    = tid >> 6;              // wave id 0..3
  const int lr   = lane & 15;             // row (A) / col (B,D) within 16-tile
  const int lg   = lane >> 4;             // k-group (A,B) / row-group (D)

  f32x4 acc[3][5];
#pragma unroll
  for (int m = 0; m < 3; ++m)
#pragma unroll
    for (int n = 0; n < 5; ++n) acc[m][n] = {0.f, 0.f, 0.f, 0.f};

  for (int kc = 0; kc < C_ / BK; ++kc) {
    const int k0 = kc * BK;
    __syncthreads();  // prev iteration's frag reads done before overwrite

    // ---- stage W hi/lo: 3 matrices x 64 rows x 32 halves each plane ----
#pragma unroll
    for (int it = 0; it < 6; ++it) {
      int v   = tid + 256 * it;           // 0..1535 half4-groups per plane
      int m   = v >> 9;                   // /512
      int rem = v & 511;
      int row = rem >> 3;
      int jv  = rem & 7;                  // half4 within row
      size_t g = ((size_t)(m * O_ + obase + row)) * C_ + (k0 + jv * 4);
      half4_t h = *reinterpret_cast<const half4_t*>(whiG + g);
      half4_t l = *reinterpret_cast<const half4_t*>(wloG + g);
      int off = (m * 64 + row) * WSTRIDE + jv * 4;
      *reinterpret_cast<half4_t*>(Whi + off) = h;
      *reinterpret_cast<half4_t*>(Wlo + off) = l;
    }

    // ---- stage X transposed [t][k] + on-the-fly hi/lo split ----
#pragma unroll
    for (int it = 0; it < 3; ++it) {
      int idx = tid + 256 * it;
      if (idx < 640) {                    // 32 rows x 20 float4
        int k  = idx / 20;
        int jt = idx % 20;
        int tl = jt * 4;
        int tg = tbase + tl;
        const float* px = xb + (size_t)(k0 + k) * T_ + tg;
        float xe[4];
        if (tg >= 0 && tg + 3 < T_) {
          float4 xv = *reinterpret_cast<const float4*>(px);
          xe[0] = xv.x; xe[1] = xv.y; xe[2] = xv.z; xe[3] = xv.w;
        } else {
#pragma unroll
          for (int e = 0; e < 4; ++e)
            xe[e] = (tg + e >= 0 && tg + e < T_) ? px[e] : 0.0f;
        }
#pragma unroll
        for (int e = 0; e < 4; ++e) {
          _Float16 hi = (_Float16)xe[e];
          _Float16 lo = (_Float16)(xe[e] - (float)hi);
          int off = (tl + e) * WSTRIDE + k;
          Xhi[off] = hi;
          Xlo[off] = lo;
        }
      }
    }
    __syncthreads();

    // ---- fragment loads (b128) + MFMA ----
    half8_t ahi[3], alo[3], bhi[5], blo[5];
#pragma unroll
    for (int m = 0; m < 3; ++m) {
      int off = (m * 64 + 16 * w + lr) * WSTRIDE + lg * 8;
      ahi[m] = *reinterpret_cast<const half8_t*>(Whi + off);
      alo[m] = *reinterpret_cast<const half8_t*>(Wlo + off);
    }
#pragma unroll
    for (int n = 0; n < 5; ++n) {
      int off = (16 * n + lr) * WSTRIDE + lg * 8;
      bhi[n] = *reinterpret_cast<const half8_t*>(Xhi + off);
      blo[n] = *reinterpret_cast<const half8_t*>(Xlo + off);
    }
#pragma unroll
    for (int m = 0; m < 3; ++m)
#pragma unroll
      for (int n = 0; n < 5; ++n) {
        acc[m][n] = __builtin_amdgcn_mfma_f32_16x16x32_f16(ahi[m], bhi[n], acc[m][n], 0, 0, 0);
        acc[m][n] = __builtin_amdgcn_mfma_f32_16x16x32_f16(ahi[m], blo[n], acc[m][n], 0, 0, 0);
        acc[m][n] = __builtin_amdgcn_mfma_f32_16x16x32_f16(alo[m], bhi[n], acc[m][n], 0, 0, 0);
      }
  }

  __syncthreads();  // all frag reads done; reuse LDS for QKV
  // ---- spill accumulators to LDS (D layout: col=lane&15, row=(lane>>4)*4+i) ----
#pragma unroll
  for (int m = 0; m < 3; ++m)
#pragma unroll
    for (int n = 0; n < 5; ++n)
#pragma unroll
      for (int i = 0; i < 4; ++i) {
        int row = 16 * w + 4 * lg + i;
        int col = 16 * n + lr;
        QKV[(m * 64 + row) * QSTRIDE + col] = acc[m][n][i];
      }
  __syncthreads();

  // ---- per-channel 3-tap softmax attention + store ----
#pragma unroll
  for (int it = 0; it < 16; ++it) {
    int ol = 16 * w + it;
    int j  = 8 + lane;                     // ext column of this output
    const float* q_ = QKV + (size_t)ol * QSTRIDE;
    const float* k_ = QKV + (size_t)(64 + ol) * QSTRIDE;
    const float* v_ = QKV + (size_t)(128 + ol) * QSTRIDE;
    float q  = q_[j];
    float s0 = q * k_[j - 4];
    float s1 = q * k_[j];
    float s2 = q * k_[j + 4];
    float mx = fmaxf(fmaxf(s0, s1), s2);
    float e0 = __expf(s0 - mx);
    float e1 = __expf(s1 - mx);
    float e2 = __expf(s2 - mx);
    float inv = 1.0f / (e0 + e1 + e2);
    float o  = (e0 * v_[j - 4] + e1 * v_[j] + e2 * v_[j + 4]) * inv;
    out[((size_t)b * O_ + obase + ol) * T_ + tb * BNO + lane] = o;
  }
}

extern "C" void kernel_launch(void* const* d_in, const int* in_sizes, int n_in,
                              void* d_out, int out_size, void* d_ws, size_t ws_size,
                              hipStream_t stream) {
  const float* x  = (const float*)d_in[0];
  const float* wq = (const float*)d_in[1];
  const float* wk = (const float*)d_in[2];
  const float* wv = (const float*)d_in[3];
  float* out = (float*)d_out;

  _Float16* whi = (_Float16*)d_ws;            // 3*512*512 halves = 1.5 MiB
  _Float16* wlo = whi + 3 * 262144;           // + 1.5 MiB  (needs ws_size >= 3 MiB)

  pack_w_kernel<<<768, 256, 0, stream>>>(wq, wk, wv, whi, wlo);
  fused_kernel<<<dim3(O_ / BM, T_ / BNO, B_), 256, 0, stream>>>(x, whi, wlo, out);
}

// Round 4
// 332.908 us; speedup vs baseline: 1.5593x; 1.5593x over previous
//
#include <hip/hip_runtime.h>
#include <hip/hip_bf16.h>
#include <stdint.h>

#define B_   16
#define C_   512
#define T_   2048
#define O_   512

#define STR  40          // LDS row stride in halves (80 B, 16B-aligned rows)
#define QS   84          // epilogue f32 row stride

// LDS half-offsets (image layout == LDS layout)
#define WHI_OFF 0
#define WLO_OFF 7680     // 192*40
#define XHI_OFF 15360    // WLO_OFF + 192*40
#define XLO_OFF 18560    // XHI_OFF + 80*40
#define LDS_HALVES 22016 // 44,032 B (43 KiB staged + 512 B tail)

#define WCHUNK 30720u    // bytes per (ob,kc) W image chunk (2*192*80)
#define XCHUNK 13312u    // bytes per (b,tb,kc) X image chunk (2*80*80 + 512 pad)
#define WIMG_BYTES (128ull * WCHUNK)     // 3,932,160
#define XIMG_BYTES (8192ull * XCHUNK)    // 109,051,904

typedef _Float16 half4_t __attribute__((ext_vector_type(4)));
typedef _Float16 half8_t __attribute__((ext_vector_type(8)));
typedef float    f32x4   __attribute__((ext_vector_type(4)));

__device__ __forceinline__ void load_lds16(const void* g, void* l) {
  __builtin_amdgcn_global_load_lds(
      (const __attribute__((address_space(1))) uint32_t*)g,
      (__attribute__((address_space(3))) uint32_t*)l, 16, 0, 0);
}

// ---------- pack W image: [ob=8][kc=16][pl=2][192 rows][40 halves], W scaled x64 ----------
__global__ __launch_bounds__(256) void pack_w_img(
    const float* __restrict__ wq, const float* __restrict__ wk,
    const float* __restrict__ wv, _Float16* __restrict__ wimg) {
  int t = blockIdx.x * 256 + threadIdx.x;     // 491,520 tasks (half4 each)
  int j4  = t % 10;
  int rem = t / 10;
  int row = rem % 192;
  int pl  = (rem / 192) & 1;
  int kc  = (rem / 384) & 15;
  int ob  = rem / 6144;
  const float* src = (row < 64) ? wq : (row < 128) ? wk : wv;
  int r = row & 63;
  half4_t o4 = {(_Float16)0, (_Float16)0, (_Float16)0, (_Float16)0};
  if (j4 < 8) {
    const float* p = src + ((size_t)(ob * 64 + r)) * 512 + kc * 32 + j4 * 4;
    float4 v = *reinterpret_cast<const float4*>(p);
    float vv[4] = {v.x, v.y, v.z, v.w};
#pragma unroll
    for (int e = 0; e < 4; ++e) {
      float s = vv[e] * 64.0f;                // keep wlo out of f16 subnormals
      _Float16 hi = (_Float16)s;
      o4[e] = pl ? (_Float16)(s - (float)hi) : hi;
    }
  }
  *reinterpret_cast<half4_t*>(wimg + ((size_t)(ob * 16 + kc)) * 15360 +
                              pl * 7680 + row * 40 + j4 * 4) = o4;
}

// ---------- pack X image: [b=16][tb=32][kc=16][pl=2][80 rows(t)][40 halves(k)] ----------
__global__ __launch_bounds__(256) void pack_x_img(
    const float* __restrict__ x, _Float16* __restrict__ ximg) {
  __shared__ float tile[32 * 81];
  const int kc = blockIdx.x, tb = blockIdx.y, b = blockIdx.z;
  const int tid = threadIdx.x;
  const int tbase = tb * 64 - 8;
  const float* xb = x + ((size_t)b * 512 + kc * 32) * 2048;
  // load 32 c-rows x 80 t (zero-fill edges)
#pragma unroll
  for (int it = 0; it < 3; ++it) {
    int task = it * 256 + tid;
    if (task < 640) {
      int c = task / 20, f4 = task % 20;
      int t0 = tbase + f4 * 4;
      float* dst = tile + c * 81 + f4 * 4;
      if (t0 >= 0 && t0 + 3 < 2048) {
        float4 v4 = *reinterpret_cast<const float4*>(xb + (size_t)c * 2048 + t0);
        dst[0] = v4.x; dst[1] = v4.y; dst[2] = v4.z; dst[3] = v4.w;
      } else {
#pragma unroll
        for (int e = 0; e < 4; ++e) {
          int tg = t0 + e;
          dst[e] = ((unsigned)tg < 2048u) ? xb[(size_t)c * 2048 + tg] : 0.0f;
        }
      }
    }
  }
  __syncthreads();
  _Float16* dst = ximg + ((size_t)((b * 32 + tb) * 16 + kc)) * 6656;
#pragma unroll
  for (int it = 0; it < 7; ++it) {
    int task = it * 256 + tid;
    if (task < 1600) {
      int j4 = task % 10;
      int rw = (task / 10) % 80;
      int pl = task / 800;
      half4_t o4 = {(_Float16)0, (_Float16)0, (_Float16)0, (_Float16)0};
      if (j4 < 8) {
#pragma unroll
        for (int e = 0; e < 4; ++e) {
          float v = tile[(j4 * 4 + e) * 81 + rw];
          _Float16 hi = (_Float16)v;
          o4[e] = pl ? (_Float16)(v - (float)hi) : hi;
        }
      }
      *reinterpret_cast<half4_t*>(dst + pl * 3200 + rw * 40 + j4 * 4) = o4;
    }
  }
}

// ---------- fallback W pack: plain [3][O][C] hi/lo planes, scaled x64 ----------
__global__ __launch_bounds__(256) void pack_w_plain(
    const float* __restrict__ wq, const float* __restrict__ wk,
    const float* __restrict__ wv, _Float16* __restrict__ whi,
    _Float16* __restrict__ wlo) {
  int gid = blockIdx.x * 256 + threadIdx.x;
  int idx = gid * 4;
  int m = idx >> 18;
  int rem = idx & 262143;
  const float* src = (m == 0) ? wq : (m == 1) ? wk : wv;
  float4 xv = *reinterpret_cast<const float4*>(src + rem);
  float xs[4] = {xv.x, xv.y, xv.z, xv.w};
  half4_t h, l;
#pragma unroll
  for (int e = 0; e < 4; ++e) {
    float s = xs[e] * 64.0f;
    _Float16 hi = (_Float16)s;
    h[e] = hi;
    l[e] = (_Float16)(s - (float)hi);
  }
  *reinterpret_cast<half4_t*>(whi + (size_t)m * 262144 + rem) = h;
  *reinterpret_cast<half4_t*>(wlo + (size_t)m * 262144 + rem) = l;
}

// ---------- fused QKV GEMM (f16 split MFMA) + 3-tap softmax ----------
// grid (8 ob, 32 tb, 16 b), 256 threads (4 waves; wave w owns o-rows 16w..16w+15)
template <int MODE>
__global__ __launch_bounds__(256, 3) void fused_kernel(
    const float* __restrict__ x,
    const _Float16* __restrict__ wA,    // MODE1: wimg ; MODE0: whi plain
    const _Float16* __restrict__ wB,    // MODE0: wlo plain
    const _Float16* __restrict__ ximg,  // MODE1 only
    float* __restrict__ out) {
  __shared__ __align__(16) _Float16 smem[LDS_HALVES];
  const int tid = threadIdx.x;
  const int ob = blockIdx.x, tb = blockIdx.y, b = blockIdx.z;
  const int obase = ob * 64;
  const int lane = tid & 63, w = tid >> 6;
  const int lr = lane & 15, lg = lane >> 4;

  f32x4 acc[3][5];
#pragma unroll
  for (int m = 0; m < 3; ++m)
#pragma unroll
    for (int n = 0; n < 5; ++n) acc[m][n] = {0.f, 0.f, 0.f, 0.f};

  const char* wsrc = nullptr;
  const char* xsrc = nullptr;
  if constexpr (MODE == 1) {
    wsrc = (const char*)wA + (size_t)(ob * 16) * WCHUNK;
    xsrc = (const char*)ximg + (size_t)((b * 32 + tb) * 16) * XCHUNK;
  }

  for (int kc = 0; kc < 16; ++kc) {
    __syncthreads();  // previous iteration's fragment reads complete
    if constexpr (MODE == 1) {
      // linear memcpy of the pre-built LDS image: 43 KiB, zero address math
#pragma unroll
      for (int it = 0; it < 11; ++it) {
        int j = it * 4 + w;                  // wave-uniform
        if (j < 43) {
          const char* src = (j < 30) ? (wsrc + (size_t)kc * WCHUNK + (size_t)j * 1024)
                                     : (xsrc + (size_t)kc * XCHUNK + (size_t)(j - 30) * 1024);
          load_lds16(src + lane * 16, (char*)smem + (size_t)j * 1024);
        }
      }
    } else {
      const int k0 = kc * 32;
      // W stage: b128 copies from pre-split planes
#pragma unroll
      for (int it = 0; it < 6; ++it) {
        int c = it * 256 + tid;              // 1536 16B-chunks
        int pl = (c >= 768) ? 1 : 0;
        int cc = c - pl * 768;               // exact (768 is not pow2 -> no mask)
        int r = cc >> 2, q = cc & 3;
        int m = r >> 6, rr = r & 63;
        const _Float16* sp = (pl ? wB : wA) +
            ((size_t)(m * 512 + obase + rr)) * 512 + k0 + q * 8;
        half8_t v = *reinterpret_cast<const half8_t*>(sp);
        *reinterpret_cast<half8_t*>(smem + pl * 7680 + r * 40 + q * 8) = v;
      }
      // X stage: per-thread k-quad gather (lanes consecutive in t => coalesced),
      // half4 LDS writes (no u16 scatter)
      const int tbase = tb * 64 - 8;
#pragma unroll
      for (int it = 0; it < 3; ++it) {
        int task = it * 256 + tid;
        if (task < 640) {
          int thi = task >> 7;
          int k4 = (task >> 4) & 7;
          int t = thi * 16 + (task & 15);
          int tg = tbase + t;
          bool ok = (unsigned)tg < 2048u;
          const float* px = x + ((size_t)b * 512 + k0 + k4 * 4) * 2048 + tg;
          half4_t h4, l4;
#pragma unroll
          for (int e = 0; e < 4; ++e) {
            float v = ok ? px[(size_t)e * 2048] : 0.0f;
            _Float16 hi = (_Float16)v;
            h4[e] = hi;
            l4[e] = (_Float16)(v - (float)hi);
          }
          *reinterpret_cast<half4_t*>(smem + XHI_OFF + t * 40 + k4 * 4) = h4;
          *reinterpret_cast<half4_t*>(smem + XLO_OFF + t * 40 + k4 * 4) = l4;
        }
      }
    }
    __syncthreads();

    half8_t ahi[3], alo[3], bhi[5], blo[5];
#pragma unroll
    for (int m = 0; m < 3; ++m) {
      int off = (m * 64 + 16 * w + lr) * 40 + lg * 8;
      ahi[m] = *reinterpret_cast<const half8_t*>(smem + WHI_OFF + off);
      alo[m] = *reinterpret_cast<const half8_t*>(smem + WLO_OFF + off);
    }
#pragma unroll
    for (int n = 0; n < 5; ++n) {
      int off = (16 * n + lr) * 40 + lg * 8;
      bhi[n] = *reinterpret_cast<const half8_t*>(smem + XHI_OFF + off);
      blo[n] = *reinterpret_cast<const half8_t*>(smem + XLO_OFF + off);
    }
#pragma unroll
    for (int m = 0; m < 3; ++m)
#pragma unroll
      for (int n = 0; n < 5; ++n) {
        acc[m][n] = __builtin_amdgcn_mfma_f32_16x16x32_f16(ahi[m], bhi[n], acc[m][n], 0, 0, 0);
        acc[m][n] = __builtin_amdgcn_mfma_f32_16x16x32_f16(ahi[m], blo[n], acc[m][n], 0, 0, 0);
        acc[m][n] = __builtin_amdgcn_mfma_f32_16x16x32_f16(alo[m], bhi[n], acc[m][n], 0, 0, 0);
      }
  }

  // ---- epilogue: 2 passes of 32 o-rows, QKV staged into the (now free) 44KB ----
  const float SC_S = 1.0f / 4096.0f;  // scores carry 64^2 from W scaling
  const float SC_V = 1.0f / 64.0f;
  float* QKV = (float*)smem;
  const int colL = tid & 63;
  const int rsub = tid >> 6;
  float* outB = out + ((size_t)b * 512 + obase) * 2048 + tb * 64;
#pragma unroll
  for (int pass = 0; pass < 2; ++pass) {
    __syncthreads();  // frag reads (pass0) / prev-pass reads (pass1) complete
    if ((w >> 1) == pass) {
      int wsub = w & 1;
#pragma unroll
      for (int m = 0; m < 3; ++m)
#pragma unroll
        for (int n = 0; n < 5; ++n)
#pragma unroll
          for (int i = 0; i < 4; ++i)
            QKV[(m * 32 + 16 * wsub + 4 * lg + i) * QS + 16 * n + lr] = acc[m][n][i];
    }
    __syncthreads();
#pragma unroll
    for (int it = 0; it < 8; ++it) {
      int r = rsub * 8 + it;  // 0..31
      const float* q_ = QKV + r * QS + 8 + colL;
      const float* k_ = QKV + (32 + r) * QS + 8 + colL;
      const float* v_ = QKV + (64 + r) * QS + 8 + colL;
      float q = q_[0];
      float s0 = q * k_[-4] * SC_S;
      float s1 = q * k_[0] * SC_S;
      float s2 = q * k_[4] * SC_S;
      float mx = fmaxf(fmaxf(s0, s1), s2);
      float e0 = __expf(s0 - mx), e1 = __expf(s1 - mx), e2 = __expf(s2 - mx);
      float o = (e0 * v_[-4] + e1 * v_[0] + e2 * v_[4]) * (SC_V / (e0 + e1 + e2));
      outB[((size_t)(32 * pass + r)) * 2048 + colL] = o;
    }
  }
}

extern "C" void kernel_launch(void* const* d_in, const int* in_sizes, int n_in,
                              void* d_out, int out_size, void* d_ws, size_t ws_size,
                              hipStream_t stream) {
  (void)in_sizes; (void)n_in; (void)out_size;
  const float* x = (const float*)d_in[0];
  const float* wq = (const float*)d_in[1];
  const float* wk = (const float*)d_in[2];
  const float* wv = (const float*)d_in[3];
  float* out = (float*)d_out;

  if (ws_size >= WIMG_BYTES + XIMG_BYTES) {
    _Float16* wimg = (_Float16*)d_ws;
    _Float16* ximg = (_Float16*)((char*)d_ws + WIMG_BYTES);
    pack_w_img<<<1920, 256, 0, stream>>>(wq, wk, wv, wimg);
    pack_x_img<<<dim3(16, 32, 16), 256, 0, stream>>>(x, ximg);
    fused_kernel<1><<<dim3(8, 32, 16), 256, 0, stream>>>(x, wimg, nullptr, ximg, out);
  } else {
    _Float16* whi = (_Float16*)d_ws;   // needs >= 3 MiB (proven available in R1)
    _Float16* wlo = whi + 3 * 262144;
    pack_w_plain<<<768, 256, 0, stream>>>(wq, wk, wv, whi, wlo);
    fused_kernel<0><<<dim3(8, 32, 16), 256, 0, stream>>>(x, whi, wlo, nullptr, out);
  }
}

// Round 9
// 318.269 us; speedup vs baseline: 1.6310x; 1.0460x over previous
//
#include <hip/hip_runtime.h>
#include <hip/hip_bf16.h>
#include <stdint.h>

#define B_   16
#define C_   512
#define T_   2048
#define O_   512

#define STR  40          // LDS row stride in halves (80 B, 16B-aligned rows)
#define QS   84          // epilogue f32 row stride

// LDS half-offsets (image layout == LDS layout)
#define WHI_OFF 0
#define WLO_OFF 7680     // 192*40
#define XHI_OFF 15360    // WLO_OFF + 192*40
#define XLO_OFF 18560    // XHI_OFF + 80*40
#define LDS_HALVES 22016 // 44,032 B (43 KiB staged + 512 B tail)

#define WCHUNK 30720u    // bytes per (ob,kc) W image chunk (2*192*80)
#define XCHUNK 13312u    // bytes per (b,tb,kc) X image chunk (2*80*80 + 512 pad)
#define WIMG_BYTES (128ull * WCHUNK)     // 3,932,160
#define XIMG_BYTES (8192ull * XCHUNK)    // 109,051,904

typedef _Float16 half4_t __attribute__((ext_vector_type(4)));
typedef _Float16 half8_t __attribute__((ext_vector_type(8)));
typedef float    f32x4   __attribute__((ext_vector_type(4)));

__device__ __forceinline__ void load_lds16(const void* g, void* l) {
  __builtin_amdgcn_global_load_lds(
      (const __attribute__((address_space(1))) uint32_t*)g,
      (__attribute__((address_space(3))) uint32_t*)l, 16, 0, 0);
}

// ---------- pack W image: [ob=8][kc=16][pl=2][192 rows][40 halves], W scaled x64 ----------
__global__ __launch_bounds__(256) void pack_w_img(
    const float* __restrict__ wq, const float* __restrict__ wk,
    const float* __restrict__ wv, _Float16* __restrict__ wimg) {
  int t = blockIdx.x * 256 + threadIdx.x;     // 491,520 tasks (half4 each)
  int j4  = t % 10;
  int rem = t / 10;
  int row = rem % 192;
  int pl  = (rem / 192) & 1;
  int kc  = (rem / 384) & 15;
  int ob  = rem / 6144;
  const float* src = (row < 64) ? wq : (row < 128) ? wk : wv;
  int r = row & 63;
  half4_t o4 = {(_Float16)0, (_Float16)0, (_Float16)0, (_Float16)0};
  if (j4 < 8) {
    const float* p = src + ((size_t)(ob * 64 + r)) * 512 + kc * 32 + j4 * 4;
    float4 v = *reinterpret_cast<const float4*>(p);
    float vv[4] = {v.x, v.y, v.z, v.w};
#pragma unroll
    for (int e = 0; e < 4; ++e) {
      float s = vv[e] * 64.0f;                // keep wlo out of f16 subnormals
      _Float16 hi = (_Float16)s;
      o4[e] = pl ? (_Float16)(s - (float)hi) : hi;
    }
  }
  *reinterpret_cast<half4_t*>(wimg + ((size_t)(ob * 16 + kc)) * 15360 +
                              pl * 7680 + row * 40 + j4 * 4) = o4;
}

// ---------- pack X image: [b=16][tb=32][kc=16][pl=2][80 rows(t)][40 halves(k)] ----------
// 2 kc per block: grid (8, 32, 16)
__global__ __launch_bounds__(256) void pack_x_img(
    const float* __restrict__ x, _Float16* __restrict__ ximg) {
  __shared__ float tile[64 * 81];
  const int bx = blockIdx.x, tb = blockIdx.y, b = blockIdx.z;
  const int tid = threadIdx.x;
  const int tbase = tb * 64 - 8;
  const int cb = bx * 64;                       // channel base (covers kc=2bx, 2bx+1)
  const float* xb = x + ((size_t)b * 512 + cb) * 2048;
  // load 64 c-rows x 80 t (zero-fill edges)
#pragma unroll
  for (int it = 0; it < 5; ++it) {
    int task = it * 256 + tid;                  // 1280 float4 tasks
    int c = task / 20, f4 = task % 20;
    int t0 = tbase + f4 * 4;
    float* dst = tile + c * 81 + f4 * 4;
    if (t0 >= 0 && t0 + 3 < 2048) {
      float4 v4 = *reinterpret_cast<const float4*>(xb + (size_t)c * 2048 + t0);
      dst[0] = v4.x; dst[1] = v4.y; dst[2] = v4.z; dst[3] = v4.w;
    } else {
#pragma unroll
      for (int e = 0; e < 4; ++e) {
        int tg = t0 + e;
        dst[e] = ((unsigned)tg < 2048u) ? xb[(size_t)c * 2048 + tg] : 0.0f;
      }
    }
  }
  __syncthreads();
  _Float16* dst0 = ximg + ((size_t)((b * 32 + tb) * 16 + 2 * bx)) * 6656;
#pragma unroll
  for (int it = 0; it < 13; ++it) {
    int task = it * 256 + tid;                  // 3200 half4 tasks
    if (task < 3200) {
      int kk = task / 1600;
      int r = task - kk * 1600;
      int j4 = r % 10;
      int rw = (r / 10) % 80;
      int pl = r / 800;
      half4_t o4 = {(_Float16)0, (_Float16)0, (_Float16)0, (_Float16)0};
      if (j4 < 8) {
#pragma unroll
        for (int e = 0; e < 4; ++e) {
          float v = tile[(kk * 32 + j4 * 4 + e) * 81 + rw];
          _Float16 hi = (_Float16)v;
          o4[e] = pl ? (_Float16)(v - (float)hi) : hi;
        }
      }
      *reinterpret_cast<half4_t*>(dst0 + (size_t)kk * 6656 + pl * 3200 + rw * 40 + j4 * 4) = o4;
    }
  }
}

// ---------- fallback W pack: plain [3][O][C] hi/lo planes, scaled x64 ----------
__global__ __launch_bounds__(256) void pack_w_plain(
    const float* __restrict__ wq, const float* __restrict__ wk,
    const float* __restrict__ wv, _Float16* __restrict__ whi,
    _Float16* __restrict__ wlo) {
  int gid = blockIdx.x * 256 + threadIdx.x;
  int idx = gid * 4;
  int m = idx >> 18;
  int rem = idx & 262143;
  const float* src = (m == 0) ? wq : (m == 1) ? wk : wv;
  float4 xv = *reinterpret_cast<const float4*>(src + rem);
  float xs[4] = {xv.x, xv.y, xv.z, xv.w};
  half4_t h, l;
#pragma unroll
  for (int e = 0; e < 4; ++e) {
    float s = xs[e] * 64.0f;
    _Float16 hi = (_Float16)s;
    h[e] = hi;
    l[e] = (_Float16)(s - (float)hi);
  }
  *reinterpret_cast<half4_t*>(whi + (size_t)m * 262144 + rem) = h;
  *reinterpret_cast<half4_t*>(wlo + (size_t)m * 262144 + rem) = l;
}

// ---------- fused QKV GEMM (f16 split MFMA) + 3-tap softmax ----------
// 1D grid 4096 blocks, XCD-swizzled so the 8 ob-blocks of one (b,tb) share an XCD L2.
template <int MODE>
__global__ __launch_bounds__(256, 3) void fused_kernel(
    const float* __restrict__ x,
    const _Float16* __restrict__ wA,    // MODE1: wimg ; MODE0: whi plain
    const _Float16* __restrict__ wB,    // MODE0: wlo plain
    const _Float16* __restrict__ ximg,  // MODE1 only
    float* __restrict__ out) {
  __shared__ __align__(16) _Float16 smem[LDS_HALVES];
  const int tid = threadIdx.x;
  // XCD swizzle (4096 % 8 == 0 -> bijective): hw round-robins flat%8 across XCDs;
  // give each XCD a contiguous work chunk so (b,tb) groups stay XCD-local.
  const int flat = blockIdx.x;
  const int work = (flat & 7) * 512 + (flat >> 3);
  const int ob = work & 7;
  const int g  = work >> 3;
  const int tb = g & 31;
  const int b  = g >> 5;
  const int obase = ob * 64;
  const int lane = tid & 63, w = tid >> 6;
  const int lr = lane & 15, lg = lane >> 4;

  f32x4 acc[3][5];
#pragma unroll
  for (int m = 0; m < 3; ++m)
#pragma unroll
    for (int n = 0; n < 5; ++n) acc[m][n] = {0.f, 0.f, 0.f, 0.f};

  const char* wsrc = nullptr;
  const char* xsrc = nullptr;
  if constexpr (MODE == 1) {
    wsrc = (const char*)wA + (size_t)(ob * 16) * WCHUNK;
    xsrc = (const char*)ximg + (size_t)((b * 32 + tb) * 16) * XCHUNK;
  }

  // one K-step's 43 KiB image -> LDS, pure DMA (round-robin chunks across waves)
  auto issue_stage = [&](int kc) {
#pragma unroll
    for (int it = 0; it < 11; ++it) {
      int j = it * 4 + w;                  // wave-uniform
      if (j < 43) {
        const char* src = (j < 30) ? (wsrc + (size_t)kc * WCHUNK + (size_t)j * 1024)
                                   : (xsrc + (size_t)kc * XCHUNK + (size_t)(j - 30) * 1024);
        load_lds16(src + lane * 16, (char*)smem + (size_t)j * 1024);
      }
    }
  };

  if constexpr (MODE == 1) issue_stage(0);

  for (int kc = 0; kc < 16; ++kc) {
    if constexpr (MODE == 1) {
      __syncthreads();  // drains vmcnt(0): stage(kc) landed, all waves
    } else {
      __syncthreads();
      const int k0 = kc * 32;
      // W stage: b128 copies from pre-split planes
#pragma unroll
      for (int it = 0; it < 6; ++it) {
        int c = it * 256 + tid;              // 1536 16B-chunks
        int pl = (c >= 768) ? 1 : 0;
        int cc = c - pl * 768;
        int r = cc >> 2, q = cc & 3;
        int m = r >> 6, rr = r & 63;
        const _Float16* sp = (pl ? wB : wA) +
            ((size_t)(m * 512 + obase + rr)) * 512 + k0 + q * 8;
        half8_t v = *reinterpret_cast<const half8_t*>(sp);
        *reinterpret_cast<half8_t*>(smem + pl * 7680 + r * 40 + q * 8) = v;
      }
      const int tbase = tb * 64 - 8;
#pragma unroll
      for (int it = 0; it < 3; ++it) {
        int task = it * 256 + tid;
        if (task < 640) {
          int thi = task >> 7;
          int k4 = (task >> 4) & 7;
          int t = thi * 16 + (task & 15);
          int tg = tbase + t;
          bool ok = (unsigned)tg < 2048u;
          const float* px = x + ((size_t)b * 512 + k0 + k4 * 4) * 2048 + tg;
          half4_t h4, l4;
#pragma unroll
          for (int e = 0; e < 4; ++e) {
            float v = ok ? px[(size_t)e * 2048] : 0.0f;
            _Float16 hi = (_Float16)v;
            h4[e] = hi;
            l4[e] = (_Float16)(v - (float)hi);
          }
          *reinterpret_cast<half4_t*>(smem + XHI_OFF + t * 40 + k4 * 4) = h4;
          *reinterpret_cast<half4_t*>(smem + XLO_OFF + t * 40 + k4 * 4) = l4;
        }
      }
      __syncthreads();
    }

    // ---- fragment loads (b128): LDS(kc) -> VGPRs ----
    half8_t ahi[3], alo[3], bhi[5], blo[5];
#pragma unroll
    for (int m = 0; m < 3; ++m) {
      int off = (m * 64 + 16 * w + lr) * 40 + lg * 8;
      ahi[m] = *reinterpret_cast<const half8_t*>(smem + WHI_OFF + off);
      alo[m] = *reinterpret_cast<const half8_t*>(smem + WLO_OFF + off);
    }
#pragma unroll
    for (int n = 0; n < 5; ++n) {
      int off = (16 * n + lr) * 40 + lg * 8;
      bhi[n] = *reinterpret_cast<const half8_t*>(smem + XHI_OFF + off);
      blo[n] = *reinterpret_cast<const half8_t*>(smem + XLO_OFF + off);
    }

    if constexpr (MODE == 1) {
      __syncthreads();                     // all waves' frag reads done (lgkm drained)
      if (kc != 15) issue_stage(kc + 1);   // DMA for next step overlaps MFMA below
    }

    __builtin_amdgcn_s_setprio(1);
#pragma unroll
    for (int m = 0; m < 3; ++m)
#pragma unroll
      for (int n = 0; n < 5; ++n) {
        acc[m][n] = __builtin_amdgcn_mfma_f32_16x16x32_f16(ahi[m], bhi[n], acc[m][n], 0, 0, 0);
        acc[m][n] = __builtin_amdgcn_mfma_f32_16x16x32_f16(ahi[m], blo[n], acc[m][n], 0, 0, 0);
        acc[m][n] = __builtin_amdgcn_mfma_f32_16x16x32_f16(alo[m], bhi[n], acc[m][n], 0, 0, 0);
      }
    __builtin_amdgcn_s_setprio(0);
  }

  // ---- epilogue: 2 passes of 32 o-rows, QKV staged into the (now free) 44KB ----
  const float SC_S = 1.0f / 4096.0f;  // scores carry 64^2 from W scaling
  const float SC_V = 1.0f / 64.0f;
  float* QKV = (float*)smem;
  const int colL = tid & 63;
  const int rsub = tid >> 6;
  float* outB = out + ((size_t)b * 512 + obase) * 2048 + tb * 64;
#pragma unroll
  for (int pass = 0; pass < 2; ++pass) {
    __syncthreads();  // frag/MFMA reads (pass0) / prev-pass reads (pass1) complete
    if ((w >> 1) == pass) {
      int wsub = w & 1;
#pragma unroll
      for (int m = 0; m < 3; ++m)
#pragma unroll
        for (int n = 0; n < 5; ++n)
#pragma unroll
          for (int i = 0; i < 4; ++i)
            QKV[(m * 32 + 16 * wsub + 4 * lg + i) * QS + 16 * n + lr] = acc[m][n][i];
    }
    __syncthreads();
#pragma unroll
    for (int it = 0; it < 8; ++it) {
      int r = rsub * 8 + it;  // 0..31
      const float* q_ = QKV + r * QS + 8 + colL;
      const float* k_ = QKV + (32 + r) * QS + 8 + colL;
      const float* v_ = QKV + (64 + r) * QS + 8 + colL;
      float q = q_[0];
      float s0 = q * k_[-4] * SC_S;
      float s1 = q * k_[0] * SC_S;
      float s2 = q * k_[4] * SC_S;
      float mx = fmaxf(fmaxf(s0, s1), s2);
      float e0 = __expf(s0 - mx), e1 = __expf(s1 - mx), e2 = __expf(s2 - mx);
      float o = (e0 * v_[-4] + e1 * v_[0] + e2 * v_[4]) * (SC_V / (e0 + e1 + e2));
      outB[((size_t)(32 * pass + r)) * 2048 + colL] = o;
    }
  }
}

extern "C" void kernel_launch(void* const* d_in, const int* in_sizes, int n_in,
                              void* d_out, int out_size, void* d_ws, size_t ws_size,
                              hipStream_t stream) {
  (void)in_sizes; (void)n_in; (void)out_size;
  const float* x = (const float*)d_in[0];
  const float* wq = (const float*)d_in[1];
  const float* wk = (const float*)d_in[2];
  const float* wv = (const float*)d_in[3];
  float* out = (float*)d_out;

  if (ws_size >= WIMG_BYTES + XIMG_BYTES) {
    _Float16* wimg = (_Float16*)d_ws;
    _Float16* ximg = (_Float16*)((char*)d_ws + WIMG_BYTES);
    pack_w_img<<<1920, 256, 0, stream>>>(wq, wk, wv, wimg);
    pack_x_img<<<dim3(8, 32, 16), 256, 0, stream>>>(x, ximg);
    fused_kernel<1><<<4096, 256, 0, stream>>>(x, wimg, nullptr, ximg, out);
  } else {
    _Float16* whi = (_Float16*)d_ws;   // needs >= 3 MiB
    _Float16* wlo = whi + 3 * 262144;
    pack_w_plain<<<768, 256, 0, stream>>>(wq, wk, wv, whi, wlo);
    fused_kernel<0><<<4096, 256, 0, stream>>>(x, whi, wlo, nullptr, out);
  }
}

// Round 10
// 239.813 us; speedup vs baseline: 2.1646x; 1.3272x over previous
//
#include <hip/hip_runtime.h>
#include <hip/hip_bf16.h>
#include <stdint.h>

#define B_   16
#define C_   512
#define T_   2048
#define O_   512

#define BNO  128         // T output tile
#define BNE  144         // T ext tile (halo 8 each side)
#define QS   148         // epilogue f32 row stride

// LDS half-offsets (image layout == LDS layout)
#define WHI_OFF 0
#define WLO_OFF 7680     // 192*40
#define XHI_OFF 15360    // WLO_OFF + 192*40
#define LDS_HALVES 21504 // 43,008 B = 42 KiB staged (last 768 B of X chunk = dead tail)

#define WCHUNK 30720u    // bytes per (ob,kc) W image chunk (2 planes * 192 * 80 B)
#define XCHUNK 12288u    // bytes per (b,tb,kc) X image chunk (144*80 B data + 768 pad)
#define WIMG_BYTES (128ull * WCHUNK)     // 3,932,160
#define XIMG_BYTES (4096ull * XCHUNK)    // 50,331,648  (16 b * 16 tb * 16 kc)

typedef _Float16 half4_t __attribute__((ext_vector_type(4)));
typedef _Float16 half8_t __attribute__((ext_vector_type(8)));
typedef float    f32x4   __attribute__((ext_vector_type(4)));

__device__ __forceinline__ void load_lds16(const void* g, void* l) {
  __builtin_amdgcn_global_load_lds(
      (const __attribute__((address_space(1))) uint32_t*)g,
      (__attribute__((address_space(3))) uint32_t*)l, 16, 0, 0);
}

// ---------- pack W image: [ob=8][kc=16][pl=2][192 rows][40 halves], W scaled x64 ----------
// (unchanged from R4 -- W image format identical)
__global__ __launch_bounds__(256) void pack_w_img(
    const float* __restrict__ wq, const float* __restrict__ wk,
    const float* __restrict__ wv, _Float16* __restrict__ wimg) {
  int t = blockIdx.x * 256 + threadIdx.x;     // 491,520 tasks (half4 each)
  int j4  = t % 10;
  int rem = t / 10;
  int row = rem % 192;
  int pl  = (rem / 192) & 1;
  int kc  = (rem / 384) & 15;
  int ob  = rem / 6144;
  const float* src = (row < 64) ? wq : (row < 128) ? wk : wv;
  int r = row & 63;
  half4_t o4 = {(_Float16)0, (_Float16)0, (_Float16)0, (_Float16)0};
  if (j4 < 8) {
    const float* p = src + ((size_t)(ob * 64 + r)) * 512 + kc * 32 + j4 * 4;
    float4 v = *reinterpret_cast<const float4*>(p);
    float vv[4] = {v.x, v.y, v.z, v.w};
#pragma unroll
    for (int e = 0; e < 4; ++e) {
      float s = vv[e] * 64.0f;                // keep wlo out of f16 subnormals
      _Float16 hi = (_Float16)s;
      o4[e] = pl ? (_Float16)(s - (float)hi) : hi;
    }
  }
  *reinterpret_cast<half4_t*>(wimg + ((size_t)(ob * 16 + kc)) * 15360 +
                              pl * 7680 + row * 40 + j4 * 4) = o4;
}

// ---------- pack X image: [b=16][tb=16][kc=16][144 rows(t)][40 halves(k)], single f16 plane ----------
// 2 kc per block: grid (8, 16, 16)
__global__ __launch_bounds__(256) void pack_x_img(
    const float* __restrict__ x, _Float16* __restrict__ ximg) {
  __shared__ float tile[64 * 145];
  const int bx = blockIdx.x, tb = blockIdx.y, b = blockIdx.z;
  const int tid = threadIdx.x;
  const int tbase = tb * BNO - 8;
  const int cb = bx * 64;                       // channels for kc = 2bx, 2bx+1
  const float* xb = x + ((size_t)b * 512 + cb) * 2048;
  // load 64 c-rows x 144 t (zero-fill edges): 2304 float4 tasks = 9*256
#pragma unroll
  for (int it = 0; it < 9; ++it) {
    int task = it * 256 + tid;
    int c = task / 36, f4 = task % 36;
    int t0 = tbase + f4 * 4;
    float* dst = tile + c * 145 + f4 * 4;
    if (t0 >= 0 && t0 + 3 < 2048) {
      float4 v4 = *reinterpret_cast<const float4*>(xb + (size_t)c * 2048 + t0);
      dst[0] = v4.x; dst[1] = v4.y; dst[2] = v4.z; dst[3] = v4.w;
    } else {
#pragma unroll
      for (int e = 0; e < 4; ++e) {
        int tg = t0 + e;
        dst[e] = ((unsigned)tg < 2048u) ? xb[(size_t)c * 2048 + tg] : 0.0f;
      }
    }
  }
  __syncthreads();
  // write transposed [t][k] f16: 2 kk x 144 rw x 10 j4 = 2880 half4 tasks
  _Float16* dst0 = ximg + ((size_t)((b * 16 + tb) * 16 + 2 * bx)) * 6144;
#pragma unroll
  for (int it = 0; it < 12; ++it) {
    int task = it * 256 + tid;
    if (task < 2880) {
      int kk = task / 1440;
      int r = task - kk * 1440;
      int j4 = r % 10;
      int rw = r / 10;                          // 0..143
      half4_t o4 = {(_Float16)0, (_Float16)0, (_Float16)0, (_Float16)0};
      if (j4 < 8) {
#pragma unroll
        for (int e = 0; e < 4; ++e)
          o4[e] = (_Float16)tile[(kk * 32 + j4 * 4 + e) * 145 + rw];
      }
      *reinterpret_cast<half4_t*>(dst0 + (size_t)kk * 6144 + rw * 40 + j4 * 4) = o4;
    }
  }
}

// ---------- fallback W pack: plain [3][O][C] hi/lo planes, scaled x64 ----------
__global__ __launch_bounds__(256) void pack_w_plain(
    const float* __restrict__ wq, const float* __restrict__ wk,
    const float* __restrict__ wv, _Float16* __restrict__ whi,
    _Float16* __restrict__ wlo) {
  int gid = blockIdx.x * 256 + threadIdx.x;
  int idx = gid * 4;
  int m = idx >> 18;
  int rem = idx & 262143;
  const float* src = (m == 0) ? wq : (m == 1) ? wk : wv;
  float4 xv = *reinterpret_cast<const float4*>(src + rem);
  float xs[4] = {xv.x, xv.y, xv.z, xv.w};
  half4_t h, l;
#pragma unroll
  for (int e = 0; e < 4; ++e) {
    float s = xs[e] * 64.0f;
    _Float16 hi = (_Float16)s;
    h[e] = hi;
    l[e] = (_Float16)(s - (float)hi);
  }
  *reinterpret_cast<half4_t*>(whi + (size_t)m * 262144 + rem) = h;
  *reinterpret_cast<half4_t*>(wlo + (size_t)m * 262144 + rem) = l;
}

// ---------- fused QKV GEMM (2-term f16 split MFMA) + 3-tap softmax ----------
// 1D grid 2048 blocks, XCD-swizzled; block = 64 o-rows x 128 t-cols; 4 waves.
template <int MODE>
__global__ __launch_bounds__(256, 2) void fused_kernel(
    const float* __restrict__ x,
    const _Float16* __restrict__ wA,    // MODE1: wimg ; MODE0: whi plain
    const _Float16* __restrict__ wB,    // MODE0: wlo plain
    const _Float16* __restrict__ ximg,  // MODE1 only
    float* __restrict__ out) {
  __shared__ __align__(16) _Float16 smem[LDS_HALVES];
  const int tid = threadIdx.x;
  // XCD swizzle (2048 % 8 == 0 -> bijective): contiguous work chunk per XCD so the
  // 8 ob-blocks of one (b,tb) share an XCD L2 (X chunk fetched once per XCD).
  const int flat = blockIdx.x;
  const int work = (flat & 7) * 256 + (flat >> 3);
  const int ob = work & 7;
  const int g  = work >> 3;               // 0..255
  const int tb = g & 15;
  const int b  = g >> 4;
  const int obase = ob * 64;
  const int lane = tid & 63, w = tid >> 6;
  const int lr = lane & 15, lg = lane >> 4;

  f32x4 acc[3][9];
#pragma unroll
  for (int m = 0; m < 3; ++m)
#pragma unroll
    for (int n = 0; n < 9; ++n) acc[m][n] = {0.f, 0.f, 0.f, 0.f};

  const char* wsrc = nullptr;
  const char* xsrc = nullptr;
  if constexpr (MODE == 1) {
    wsrc = (const char*)wA + (size_t)(ob * 16) * WCHUNK;
    xsrc = (const char*)ximg + (size_t)((b * 16 + tb) * 16) * XCHUNK;
  }

  // one K-step's 42 KiB image -> LDS, pure DMA (42 x 1 KiB chunks round-robin)
  auto issue_stage = [&](int kc) {
#pragma unroll
    for (int it = 0; it < 11; ++it) {
      int j = it * 4 + w;                  // wave-uniform
      if (j < 42) {
        const char* src = (j < 30) ? (wsrc + (size_t)kc * WCHUNK + (size_t)j * 1024)
                                   : (xsrc + (size_t)kc * XCHUNK + (size_t)(j - 30) * 1024);
        load_lds16(src + lane * 16, (char*)smem + (size_t)j * 1024);
      }
    }
  };

  if constexpr (MODE == 1) issue_stage(0);

  for (int kc = 0; kc < 16; ++kc) {
    if constexpr (MODE == 1) {
      __syncthreads();  // drains vmcnt(0): stage(kc) landed, all waves
    } else {
      __syncthreads();
      const int k0 = kc * 32;
      // W stage: b128 copies from pre-split planes (same layout as image)
#pragma unroll
      for (int it = 0; it < 6; ++it) {
        int c = it * 256 + tid;              // 1536 16B-chunks
        int pl = (c >= 768) ? 1 : 0;
        int cc = c - pl * 768;
        int r = cc >> 2, q = cc & 3;
        int m = r >> 6, rr = r & 63;
        const _Float16* sp = (pl ? wB : wA) +
            ((size_t)(m * 512 + obase + rr)) * 512 + k0 + q * 8;
        half8_t v = *reinterpret_cast<const half8_t*>(sp);
        *reinterpret_cast<half8_t*>(smem + pl * 7680 + r * 40 + q * 8) = v;
      }
      // X stage on the fly: single f16 plane, 144 t x 32 k
      const int tbase = tb * BNO - 8;
#pragma unroll
      for (int it = 0; it < 5; ++it) {
        int task = it * 256 + tid;
        if (task < 1152) {
          int t = task >> 3;
          int k4 = task & 7;
          int tg = tbase + t;
          bool ok = (unsigned)tg < 2048u;
          const float* px = x + ((size_t)b * 512 + k0 + k4 * 4) * 2048 + tg;
          half4_t h4;
#pragma unroll
          for (int e = 0; e < 4; ++e)
            h4[e] = (_Float16)(ok ? px[(size_t)e * 2048] : 0.0f);
          *reinterpret_cast<half4_t*>(smem + XHI_OFF + t * 40 + k4 * 4) = h4;
        }
      }
      __syncthreads();
    }

    // ---- fragment loads (b128): LDS(kc) -> VGPRs ----
    half8_t ahi[3], alo[3], bhi[9];
#pragma unroll
    for (int m = 0; m < 3; ++m) {
      int off = (m * 64 + 16 * w + lr) * 40 + lg * 8;
      ahi[m] = *reinterpret_cast<const half8_t*>(smem + WHI_OFF + off);
      alo[m] = *reinterpret_cast<const half8_t*>(smem + WLO_OFF + off);
    }
#pragma unroll
    for (int n = 0; n < 9; ++n) {
      int off = (16 * n + lr) * 40 + lg * 8;
      bhi[n] = *reinterpret_cast<const half8_t*>(smem + XHI_OFF + off);
    }

    if constexpr (MODE == 1) {
      __syncthreads();                     // all waves' frag reads done (lgkm drained)
      if (kc != 15) issue_stage(kc + 1);   // DMA for next step overlaps MFMA below
    }

    __builtin_amdgcn_s_setprio(1);
#pragma unroll
    for (int m = 0; m < 3; ++m)
#pragma unroll
      for (int n = 0; n < 9; ++n) {
        acc[m][n] = __builtin_amdgcn_mfma_f32_16x16x32_f16(ahi[m], bhi[n], acc[m][n], 0, 0, 0);
        acc[m][n] = __builtin_amdgcn_mfma_f32_16x16x32_f16(alo[m], bhi[n], acc[m][n], 0, 0, 0);
      }
    __builtin_amdgcn_s_setprio(0);
  }

  // ---- epilogue: 4 passes of 16 o-rows, QKV [3*16][QS] f32 in the staging LDS ----
  const float SC_S = 1.0f / 4096.0f;  // scores carry 64^2 from W scaling
  const float SC_V = 1.0f / 64.0f;
  float* QKV = (float*)smem;          // 3*16*148*4 = 28,416 B < 43,008
  const int colL = tid & 127;
  const int rh = tid >> 7;
  float* outB = out + ((size_t)b * 512 + obase) * 2048 + tb * BNO;
#pragma unroll
  for (int pass = 0; pass < 4; ++pass) {
    __syncthreads();  // frag/MFMA LDS reads (pass0) / prev-pass reads complete
    if (w == pass) {
#pragma unroll
      for (int m = 0; m < 3; ++m)
#pragma unroll
        for (int n = 0; n < 9; ++n)
#pragma unroll
          for (int i = 0; i < 4; ++i)
            QKV[(m * 16 + 4 * lg + i) * QS + 16 * n + lr] = acc[m][n][i];
    }
    __syncthreads();
#pragma unroll
    for (int it = 0; it < 8; ++it) {
      int r = it * 2 + rh;  // 0..15
      const float* q_ = QKV + r * QS + 8 + colL;
      const float* k_ = QKV + (16 + r) * QS + 8 + colL;
      const float* v_ = QKV + (32 + r) * QS + 8 + colL;
      float q = q_[0];
      float s0 = q * k_[-4] * SC_S;
      float s1 = q * k_[0] * SC_S;
      float s2 = q * k_[4] * SC_S;
      float mx = fmaxf(fmaxf(s0, s1), s2);
      float e0 = __expf(s0 - mx), e1 = __expf(s1 - mx), e2 = __expf(s2 - mx);
      float o = (e0 * v_[-4] + e1 * v_[0] + e2 * v_[4]) * (SC_V / (e0 + e1 + e2));
      outB[((size_t)(16 * pass + r)) * 2048 + colL] = o;
    }
  }
}

extern "C" void kernel_launch(void* const* d_in, const int* in_sizes, int n_in,
                              void* d_out, int out_size, void* d_ws, size_t ws_size,
                              hipStream_t stream) {
  (void)in_sizes; (void)n_in; (void)out_size;
  const float* x = (const float*)d_in[0];
  const float* wq = (const float*)d_in[1];
  const float* wk = (const float*)d_in[2];
  const float* wv = (const float*)d_in[3];
  float* out = (float*)d_out;

  if (ws_size >= WIMG_BYTES + XIMG_BYTES) {   // 54.3 MB (R4/R9 ran MODE1 at 113 MB)
    _Float16* wimg = (_Float16*)d_ws;
    _Float16* ximg = (_Float16*)((char*)d_ws + WIMG_BYTES);
    pack_w_img<<<1920, 256, 0, stream>>>(wq, wk, wv, wimg);
    pack_x_img<<<dim3(8, 16, 16), 256, 0, stream>>>(x, ximg);
    fused_kernel<1><<<2048, 256, 0, stream>>>(x, wimg, nullptr, ximg, out);
  } else {
    _Float16* whi = (_Float16*)d_ws;   // needs >= 3 MiB
    _Float16* wlo = whi + 3 * 262144;
    pack_w_plain<<<768, 256, 0, stream>>>(wq, wk, wv, whi, wlo);
    fused_kernel<0><<<2048, 256, 0, stream>>>(x, whi, wlo, nullptr, out);
  }
}